// Round 7
// baseline (205.003 us; speedup 1.0000x reference)
//
#include <hip/hip_runtime.h>
#include <hip/hip_bf16.h>
#include <cstdint>

// Problem: B=256, N0=64, D0=128, N1=64, D1=128 (all fp32 in/out).
// u[b,n1,n0,d1] = sum_d0 x[b,n0,d0]*W[n1,n0,d0,d1]
// s = sum_n0 u ; logit = (u . s)/sqrt(128) ; c = softmax_n1(logit) + bias
// out[b,n1,d1] = sum_n0 u*c
//
// ws layout: u bf16 [B][N1][N0][D1]      @ 0          (268435456 B)
//            logits f32 [B][N1][N0]      @ 268435456  (4194304 B)
//            cc/xbf shared region        @ 272629760  (4194304 B)
//
// REGISTER BUDGET RULE (R4/R5 lesson): unified VGPR+AGPR must stay <= 128/wave
// (4 waves/SIMD) or occupancy collapses. Wave-tile 64x32 (acc=32) + W depth-3
// regs (24) + misc ~50 ≈ 110 — fits the (512,4) cap of 128 without spill.

#define BB 256
#define NN0 64
#define DD0 128
#define NN1 64
#define DD1 128

typedef __attribute__((ext_vector_type(8))) short bf16x8;
typedef __attribute__((ext_vector_type(4))) float f32x4;

__device__ __forceinline__ ushort f2bf(float f) {
  uint32_t b = __float_as_uint(f);
  b += 0x7FFFu + ((b >> 16) & 1u);      // RNE
  return (ushort)(b >> 16);
}
__device__ __forceinline__ float bf2f(ushort h) {
  return __uint_as_float(((uint32_t)h) << 16);
}

__device__ __forceinline__ void gld_lds16(const void* g, void* l) {
  __builtin_amdgcn_global_load_lds(
      (const __attribute__((address_space(1))) void*)g,
      (__attribute__((address_space(3))) void*)l, 16, 0, 0);
}

// barrier that does NOT drain vmcnt (W prefetch stays in flight across it).
__device__ __forceinline__ void bar_lgkm() {
  asm volatile("s_waitcnt lgkmcnt(0)" ::: "memory");
  __builtin_amdgcn_s_barrier();
  __builtin_amdgcn_sched_barrier(0);
}

// ---------------- Px: x fp32 -> bf16
__global__ __launch_bounds__(512) void px_cvt(
    const float* __restrict__ x, ushort* __restrict__ xbf)
{
  int i = blockIdx.x * 512 + threadIdx.x;   // 524288 float4 chunks total
  float4 v = *reinterpret_cast<const float4*>(x + (size_t)i * 4);
  ushort4 h;
  h.x = f2bf(v.x); h.y = f2bf(v.y); h.z = f2bf(v.z); h.w = f2bf(v.w);
  *reinterpret_cast<ushort4*>(xbf + (size_t)i * 4) = h;
}

// ---------------- K1: block = (n1, n0, b-half). M=128(b) x N=128(d1), K=128.
// A staged ONCE (full K) via global_load_lds. ALL W for the block issued in
// the prologue (depth-3 reg buffers; step-3 reuses w0's regs after pack0):
// steady-state k-steps never wait on HBM. lgkm-only barriers keep loads in
// flight (T3/T4). LDS: A 32K + B 8K*2 = 48KB -> 2 blocks/CU at <=128 regs.
__global__ __launch_bounds__(512, 4) void k1_gemm(
    const ushort* __restrict__ xbf, const float* __restrict__ W,
    ushort* __restrict__ u)
{
  __shared__ __align__(16) char lds[49152];
  char* Alds = lds;                          // 128 rows(b) x 256B (k=128), XOR-swz
  char* Bl[2] = { lds + 32768, lds + 40960 };// 128 rows(d1) x 64B (32 k), swz

  // XCD-chunk: 8192 blocks = 8 XCDs x 1024; XCD owns n0 in [x*8,x*8+8).
  // bh-pairs (local 2k,2k+1) are q,q+8: same XCD, adjacent in time -> W L2-hit.
  const int q = blockIdx.x;
  const int local = (q >> 3) | ((q & 7) << 10);   // bijective (8192 = 8*1024)
  const int n0 = local >> 7;
  const int n1 = (local >> 1) & 63;
  const int bh = local & 1;
  const int t = threadIdx.x;
  const int lane = t & 63, wave = t >> 6;
  const int wm = wave >> 2, wn = wave & 3;   // 2 M-waves(64b) x 4 N-waves(32 d1)

  const ushort* xb = xbf + n0 * DD0 + (size_t)bh * 128 * 8192;  // + row*8192 + d0
  const float* Wb = W + ((size_t)n1 * NN0 + n0) * (DD0 * DD1);  // [d0][d1]
  ushort* ub = u + ((size_t)n1 * 8192 + (size_t)n0 * 128 + (size_t)bh * 128 * 524288);

  f32x4 acc[4][2];
#pragma unroll
  for (int a = 0; a < 4; ++a)
#pragma unroll
    for (int b = 0; b < 2; ++b) acc[a][b] = {0.f, 0.f, 0.f, 0.f};

  // W gather: one chunk per thread: d1 = t&127, kc = t>>7 (8 consecutive k's)
  const int gd1 = t & 127, gkc = t >> 7;
  const int bbyte = (gd1 * 64 + gkc * 16) ^ ((gd1 & 3) << 4) ^ (((gd1 >> 2) & 1) << 6);
  float w0[8], w1[8], w2[8];

#define LOADW(hh, ks)                                                         \
  {                                                                           \
    _Pragma("unroll")                                                         \
    for (int j = 0; j < 8; ++j)                                               \
      hh[j] = Wb[(size_t)((ks) * 32 + gkc * 8 + j) * 128 + gd1];              \
  }
#define PACKB(bi, hh)                                                         \
  {                                                                           \
    uint32_t p0 = (uint32_t)f2bf(hh[0]) | ((uint32_t)f2bf(hh[1]) << 16);      \
    uint32_t p1 = (uint32_t)f2bf(hh[2]) | ((uint32_t)f2bf(hh[3]) << 16);      \
    uint32_t p2 = (uint32_t)f2bf(hh[4]) | ((uint32_t)f2bf(hh[5]) << 16);      \
    uint32_t p3 = (uint32_t)f2bf(hh[6]) | ((uint32_t)f2bf(hh[7]) << 16);      \
    *reinterpret_cast<uint4*>(Bl[bi] + bbyte) = make_uint4(p0, p1, p2, p3);   \
  }
#define MFMA_STEP(ks, bi)                                                     \
  {                                                                           \
    const int kb16 = (lane >> 4);                                             \
    const int ka = (ks) * 32 + kb16 * 8;                                      \
    bf16x8 af[4], bfr[2];                                                     \
    _Pragma("unroll")                                                         \
    for (int mf = 0; mf < 4; ++mf) {                                          \
      int row = wm * 64 + mf * 16 + (lane & 15);                              \
      int byte = (row * 256 + ka * 2) ^ ((row & 7) << 4);                     \
      af[mf] = *reinterpret_cast<const bf16x8*>(Alds + byte);                 \
    }                                                                         \
    _Pragma("unroll")                                                         \
    for (int nf = 0; nf < 2; ++nf) {                                          \
      int n = wn * 32 + nf * 16 + (lane & 15);                                \
      int byte = (n * 64 + kb16 * 16) ^ ((n & 3) << 4) ^ (((n >> 2) & 1) << 6); \
      bfr[nf] = *reinterpret_cast<const bf16x8*>(Bl[bi] + byte);              \
    }                                                                         \
    _Pragma("unroll")                                                         \
    for (int mf = 0; mf < 4; ++mf)                                            \
      _Pragma("unroll")                                                       \
      for (int nf = 0; nf < 2; ++nf)                                          \
        acc[mf][nf] = __builtin_amdgcn_mfma_f32_16x16x32_bf16(af[mf], bfr[nf], acc[mf][nf], 0, 0, 0); \
  }

  // ---- prologue. Issue order: A-DMA oldest, then W0,W1,W2.
  // pack0's compiler vm-wait (counted: leaves W1,W2 in flight) implies A-DMA
  // retired (in-order vmcnt) -> A visible before the first barrier.
#pragma unroll
  for (int s = 0; s < 4; ++s) {
    int seg = wave * 4 + s;                  // 32 segs x 1024B (4 rows of 256B)
    int row = seg * 4 + (lane >> 4);
    int srcc = (lane & 15) ^ (row & 7);      // source pre-swizzle (linear dest)
    gld_lds16(xb + (size_t)row * 8192 + srcc * 8, Alds + seg * 1024);
  }
  __builtin_amdgcn_sched_barrier(0);
  LOADW(w0, 0);
  __builtin_amdgcn_sched_barrier(0);
  LOADW(w1, 1);
  __builtin_amdgcn_sched_barrier(0);
  LOADW(w2, 2);
  __builtin_amdgcn_sched_barrier(0);
  PACKB(0, w0);                              // waits w0; w1,w2 fly
  LOADW(w0, 3);                              // step-3 load reuses w0 regs
  __builtin_amdgcn_sched_barrier(0);
  bar_lgkm();

  // ---- 4 k-steps; pack(k+1) runs beside MFMA(k) (other buffer); one
  // lgkm-barrier per step; no vmcnt drain anywhere in the loop.
  PACKB(1, w1);                              // waits w1; w2, w3 fly
  __builtin_amdgcn_sched_barrier(0);
  MFMA_STEP(0, 0);
  bar_lgkm();

  PACKB(0, w2);                              // waits w2; w3 flies
  __builtin_amdgcn_sched_barrier(0);
  MFMA_STEP(1, 1);
  bar_lgkm();

  PACKB(1, w0);                              // waits w3 (in w0 regs)
  __builtin_amdgcn_sched_barrier(0);
  MFMA_STEP(2, 0);
  bar_lgkm();

  MFMA_STEP(3, 1);

  // ---- epilogue: stage u rows through A-region (32KB = 128 rows x 256B)
  bar_lgkm();                                // all MFMA ds_reads of A done
#pragma unroll
  for (int mf = 0; mf < 4; ++mf) {
#pragma unroll
    for (int nf = 0; nf < 2; ++nf) {
      int col = wn * 32 + nf * 16 + (lane & 15);
#pragma unroll
      for (int j = 0; j < 4; ++j) {
        int rr = wm * 64 + mf * 16 + (lane >> 4) * 4 + j;
        int byte = (rr * 256 + col * 2) ^ ((rr & 7) << 4);
        *reinterpret_cast<ushort*>(Alds + byte) = f2bf(acc[mf][nf][j]);
      }
    }
  }
  bar_lgkm();
#pragma unroll
  for (int ci = 0; ci < 4; ++ci) {
    int c = t + ci * 512;                    // 2048 x 16B chunks = 32KB
    int rowl = c >> 4;
    int cb = (c & 15) * 16;
    int sbyte = (rowl * 256 + cb) ^ ((rowl & 7) << 4);
    uint4 v = *reinterpret_cast<uint4*>(Alds + sbyte);
    *reinterpret_cast<uint4*>(ub + (size_t)rowl * 524288 + cb / 2) = v;
  }
#undef LOADW
#undef PACKB
#undef MFMA_STEP
}

// ---------------- K2: s = sum_n0 u ; logits = (u . s)/sqrt(128)
// Grid reversed: reads the u K1 wrote last first (L3-resident).
__global__ __launch_bounds__(256) void k2_logits(
    const ushort* __restrict__ u, float* __restrict__ logits)
{
  const int bid = gridDim.x - 1 - blockIdx.x;  // b*64 + n1, reversed
  const ushort* up = u + (size_t)bid * 8192;   // [n0][d1] 64x128
  const int t = threadIdx.x;

  __shared__ float part[8][128];
  __shared__ float sS[128];
  __shared__ float part2[256];

  {
    int d4 = (t & 31) * 4;
    int g = t >> 5;                     // n0 group of 8
    float4 a = {0, 0, 0, 0};
    for (int n0 = g * 8; n0 < g * 8 + 8; ++n0) {
      ushort4 v = *reinterpret_cast<const ushort4*>(up + n0 * 128 + d4);
      a.x += bf2f(v.x); a.y += bf2f(v.y); a.z += bf2f(v.z); a.w += bf2f(v.w);
    }
    *reinterpret_cast<float4*>(&part[g][d4]) = a;
  }
  __syncthreads();
  if (t < 128) {
    float s = 0;
#pragma unroll
    for (int g = 0; g < 8; ++g) s += part[g][t];
    sS[t] = s;
  }
  __syncthreads();
  {
    int n0 = t >> 2, qq = t & 3;
    float acc = 0;
#pragma unroll
    for (int j = 0; j < 32; j += 4) {
      int d = qq * 32 + j;
      ushort4 v = *reinterpret_cast<const ushort4*>(up + n0 * 128 + d);
      acc += bf2f(v.x) * sS[d] + bf2f(v.y) * sS[d + 1] + bf2f(v.z) * sS[d + 2] + bf2f(v.w) * sS[d + 3];
    }
    part2[t] = acc;
  }
  __syncthreads();
  if (t < 64) {
    float l = (part2[t * 4] + part2[t * 4 + 1] + part2[t * 4 + 2] + part2[t * 4 + 3]) * 0.08838834764831845f;
    logits[(size_t)bid * 64 + t] = l;
  }
}

// ---------------- K3: softmax over n1 (per (b,n0)) + bias
__global__ __launch_bounds__(64) void k3_softmax(
    const float* __restrict__ logits, const float* __restrict__ bias,
    float* __restrict__ cc)
{
  const int b = blockIdx.x;
  const int t = threadIdx.x;            // = n0
  __shared__ float L[64][64];           // [n1][n0]
  const float* lp = logits + (size_t)b * 4096;
  for (int i = 0; i < 64; ++i) L[i][t] = lp[i * 64 + t];
  __syncthreads();
  float m = -1e30f;
#pragma unroll
  for (int n1 = 0; n1 < 64; ++n1) m = fmaxf(m, L[n1][t]);
  float sum = 0.f;
#pragma unroll
  for (int n1 = 0; n1 < 64; ++n1) {
    float e = __expf(L[n1][t] - m);
    L[n1][t] = e;
    sum += e;
  }
  float inv = 1.0f / sum;
  float* cp = cc + (size_t)b * 4096;
  for (int n1 = 0; n1 < 64; ++n1)
    cp[n1 * 64 + t] = L[n1][t] * inv + bias[n1 * 64 + t];
}

// ---------------- K4: out[b,n1,d1] = sum_n0 u * c
__global__ __launch_bounds__(128) void k4_out(
    const ushort* __restrict__ u, const float* __restrict__ cc,
    float* __restrict__ out)
{
  const int bid = blockIdx.x;           // b*64 + n1
  const ushort* up = u + (size_t)bid * 8192;
  const int t = threadIdx.x;
  __shared__ float cL[64];
  __shared__ float part[4][128];
  if (t < 64) cL[t] = cc[(size_t)bid * 64 + t];
  __syncthreads();
  int d4 = (t & 31) * 4, g = t >> 5;    // g: n0 group of 16
  float4 a = {0, 0, 0, 0};
  for (int n0 = g * 16; n0 < g * 16 + 16; ++n0) {
    ushort4 v = *reinterpret_cast<const ushort4*>(up + n0 * 128 + d4);
    float c = cL[n0];
    a.x += bf2f(v.x) * c; a.y += bf2f(v.y) * c; a.z += bf2f(v.z) * c; a.w += bf2f(v.w) * c;
  }
  *reinterpret_cast<float4*>(&part[g][d4]) = a;
  __syncthreads();
  if (t < 128) {
    float r = part[0][t] + part[1][t] + part[2][t] + part[3][t];
    out[(size_t)bid * 128 + t] = r;
  }
}

extern "C" void kernel_launch(void* const* d_in, const int* in_sizes, int n_in,
                              void* d_out, int out_size, void* d_ws, size_t ws_size,
                              hipStream_t stream) {
  const float* x = (const float*)d_in[0];
  const float* W = (const float*)d_in[1];
  const float* bias = (const float*)d_in[2];
  float* out = (float*)d_out;

  ushort* u = (ushort*)d_ws;                                   // 268435456 B
  float* logits = (float*)((char*)d_ws + 268435456u);          // 4194304 B
  char* ccxbf = (char*)d_ws + 272629760u;                      // 4194304 B shared
  ushort* xbf = (ushort*)ccxbf;     // live Px..K1
  float* cc = (float*)ccxbf;        // live K3..K4 (overwrites xbf after K1 done)

  hipLaunchKernelGGL(px_cvt,     dim3(1024),     dim3(512), 0, stream, x, xbf);
  hipLaunchKernelGGL(k1_gemm,    dim3(8192),     dim3(512), 0, stream, xbf, W, u);
  hipLaunchKernelGGL(k2_logits,  dim3(BB * NN1), dim3(256), 0, stream, u, logits);
  hipLaunchKernelGGL(k3_softmax, dim3(BB),       dim3(64),  0, stream, logits, bias, cc);
  hipLaunchKernelGGL(k4_out,     dim3(BB * NN1), dim3(128), 0, stream, u, cc, out);
}

// Round 9
// 194.951 us; speedup vs baseline: 1.0516x; 1.0516x over previous
//
#include <hip/hip_runtime.h>
#include <hip/hip_bf16.h>
#include <cstdint>

// Problem: B=256, N0=64, D0=128, N1=64, D1=128 (all fp32 in/out).
// u[b,n1,n0,d1] = sum_d0 x[b,n0,d0]*W[n1,n0,d0,d1]
// s = sum_n0 u ; logit = (u . s)/sqrt(128) ; c = softmax_n1(logit) + bias
// out[b,n1,d1] = sum_n0 u*c
//
// ws layout: u bf16 [B][N1][N0][D1]      @ 0          (268435456 B)
//            logits f32 [B][N1][N0]      @ 268435456  (4194304 B)
//            cc/xbf shared region        @ 272629760  (4194304 B)
//
// REGISTER BUDGET RULE (R4/R5): unified VGPR+AGPR <= 128/wave or occupancy
// collapses. L3 RULE (R8): W is streamed with nontemporal loads so the
// 256MB Infinity Cache stays dedicated to u (268MB), making K2/K4's u
// re-reads L3-hits instead of HBM traffic.
// NOTE: __builtin_nontemporal_load needs scalar or ext_vector_type pointers —
// HIP's float4 struct is rejected (R8 compile fail). Use f32x4 typedef.

#define BB 256
#define NN0 64
#define DD0 128
#define NN1 64
#define DD1 128

typedef __attribute__((ext_vector_type(8))) short bf16x8;
typedef __attribute__((ext_vector_type(4))) float f32x4;

__device__ __forceinline__ ushort f2bf(float f) {
  uint32_t b = __float_as_uint(f);
  b += 0x7FFFu + ((b >> 16) & 1u);      // RNE
  return (ushort)(b >> 16);
}
__device__ __forceinline__ float bf2f(ushort h) {
  return __uint_as_float(((uint32_t)h) << 16);
}

__device__ __forceinline__ void gld_lds16(const void* g, void* l) {
  __builtin_amdgcn_global_load_lds(
      (const __attribute__((address_space(1))) void*)g,
      (__attribute__((address_space(3))) void*)l, 16, 0, 0);
}

// barrier that does NOT drain vmcnt (W prefetch stays in flight across it).
__device__ __forceinline__ void bar_lgkm() {
  asm volatile("s_waitcnt lgkmcnt(0)" ::: "memory");
  __builtin_amdgcn_s_barrier();
  __builtin_amdgcn_sched_barrier(0);
}

// ---------------- Px: x fp32 -> bf16 (x read is single-use: nontemporal)
__global__ __launch_bounds__(512) void px_cvt(
    const float* __restrict__ x, ushort* __restrict__ xbf)
{
  int i = blockIdx.x * 512 + threadIdx.x;   // 524288 f32x4 chunks total
  const f32x4* src = reinterpret_cast<const f32x4*>(x) + i;
  f32x4 v = __builtin_nontemporal_load(src);
  ushort4 h;
  h.x = f2bf(v.x); h.y = f2bf(v.y); h.z = f2bf(v.z); h.w = f2bf(v.w);
  *reinterpret_cast<ushort4*>(xbf + (size_t)i * 4) = h;
}

// ---------------- K1: block = (n1, n0, b-half). M=128(b) x N=128(d1), K=128.
// A staged ONCE (full K) via global_load_lds. ALL W for the block issued in
// the prologue (depth-3 reg buffers); W loads are NONTEMPORAL (no L3 pollute).
// lgkm-only barriers keep loads in flight. LDS: A 32K + B 8K*2 = 48KB.
__global__ __launch_bounds__(512, 4) void k1_gemm(
    const ushort* __restrict__ xbf, const float* __restrict__ W,
    ushort* __restrict__ u)
{
  __shared__ __align__(16) char lds[49152];
  char* Alds = lds;                          // 128 rows(b) x 256B (k=128), XOR-swz
  char* Bl[2] = { lds + 32768, lds + 40960 };// 128 rows(d1) x 64B (32 k), swz

  // XCD-chunk: 8192 blocks = 8 XCDs x 1024; XCD owns n0 in [x*8,x*8+8).
  // bh-pairs (local 2k,2k+1) are q,q+8: same XCD, adjacent in time -> W L2-hit.
  const int q = blockIdx.x;
  const int local = (q >> 3) | ((q & 7) << 10);   // bijective (8192 = 8*1024)
  const int n0 = local >> 7;
  const int n1 = (local >> 1) & 63;
  const int bh = local & 1;
  const int t = threadIdx.x;
  const int lane = t & 63, wave = t >> 6;
  const int wm = wave >> 2, wn = wave & 3;   // 2 M-waves(64b) x 4 N-waves(32 d1)

  const ushort* xb = xbf + n0 * DD0 + (size_t)bh * 128 * 8192;  // + row*8192 + d0
  const float* Wb = W + ((size_t)n1 * NN0 + n0) * (DD0 * DD1);  // [d0][d1]
  ushort* ub = u + ((size_t)n1 * 8192 + (size_t)n0 * 128 + (size_t)bh * 128 * 524288);

  f32x4 acc[4][2];
#pragma unroll
  for (int a = 0; a < 4; ++a)
#pragma unroll
    for (int b = 0; b < 2; ++b) acc[a][b] = {0.f, 0.f, 0.f, 0.f};

  // W gather: one chunk per thread: d1 = t&127, kc = t>>7 (8 consecutive k's)
  const int gd1 = t & 127, gkc = t >> 7;
  const int bbyte = (gd1 * 64 + gkc * 16) ^ ((gd1 & 3) << 4) ^ (((gd1 >> 2) & 1) << 6);
  float w0[8], w1[8], w2[8];

#define LOADW(hh, ks)                                                         \
  {                                                                           \
    _Pragma("unroll")                                                         \
    for (int j = 0; j < 8; ++j)                                               \
      hh[j] = __builtin_nontemporal_load(                                     \
          Wb + (size_t)((ks) * 32 + gkc * 8 + j) * 128 + gd1);                \
  }
#define PACKB(bi, hh)                                                         \
  {                                                                           \
    uint32_t p0 = (uint32_t)f2bf(hh[0]) | ((uint32_t)f2bf(hh[1]) << 16);      \
    uint32_t p1 = (uint32_t)f2bf(hh[2]) | ((uint32_t)f2bf(hh[3]) << 16);      \
    uint32_t p2 = (uint32_t)f2bf(hh[4]) | ((uint32_t)f2bf(hh[5]) << 16);      \
    uint32_t p3 = (uint32_t)f2bf(hh[6]) | ((uint32_t)f2bf(hh[7]) << 16);      \
    *reinterpret_cast<uint4*>(Bl[bi] + bbyte) = make_uint4(p0, p1, p2, p3);   \
  }
#define MFMA_STEP(ks, bi)                                                     \
  {                                                                           \
    const int kb16 = (lane >> 4);                                             \
    const int ka = (ks) * 32 + kb16 * 8;                                      \
    bf16x8 af[4], bfr[2];                                                     \
    _Pragma("unroll")                                                         \
    for (int mf = 0; mf < 4; ++mf) {                                          \
      int row = wm * 64 + mf * 16 + (lane & 15);                              \
      int byte = (row * 256 + ka * 2) ^ ((row & 7) << 4);                     \
      af[mf] = *reinterpret_cast<const bf16x8*>(Alds + byte);                 \
    }                                                                         \
    _Pragma("unroll")                                                         \
    for (int nf = 0; nf < 2; ++nf) {                                          \
      int n = wn * 32 + nf * 16 + (lane & 15);                                \
      int byte = (n * 64 + kb16 * 16) ^ ((n & 3) << 4) ^ (((n >> 2) & 1) << 6); \
      bfr[nf] = *reinterpret_cast<const bf16x8*>(Bl[bi] + byte);              \
    }                                                                         \
    _Pragma("unroll")                                                         \
    for (int mf = 0; mf < 4; ++mf)                                            \
      _Pragma("unroll")                                                       \
      for (int nf = 0; nf < 2; ++nf)                                          \
        acc[mf][nf] = __builtin_amdgcn_mfma_f32_16x16x32_bf16(af[mf], bfr[nf], acc[mf][nf], 0, 0, 0); \
  }

  // ---- prologue. Issue order: A-DMA oldest, then W0,W1,W2.
#pragma unroll
  for (int s = 0; s < 4; ++s) {
    int seg = wave * 4 + s;                  // 32 segs x 1024B (4 rows of 256B)
    int row = seg * 4 + (lane >> 4);
    int srcc = (lane & 15) ^ (row & 7);      // source pre-swizzle (linear dest)
    gld_lds16(xb + (size_t)row * 8192 + srcc * 8, Alds + seg * 1024);
  }
  __builtin_amdgcn_sched_barrier(0);
  LOADW(w0, 0);
  __builtin_amdgcn_sched_barrier(0);
  LOADW(w1, 1);
  __builtin_amdgcn_sched_barrier(0);
  LOADW(w2, 2);
  __builtin_amdgcn_sched_barrier(0);
  PACKB(0, w0);                              // waits w0; w1,w2 fly
  LOADW(w0, 3);                              // step-3 load reuses w0 regs
  __builtin_amdgcn_sched_barrier(0);
  bar_lgkm();

  // ---- 4 k-steps; pack(k+1) runs beside MFMA(k); one lgkm-barrier per step.
  PACKB(1, w1);
  __builtin_amdgcn_sched_barrier(0);
  MFMA_STEP(0, 0);
  bar_lgkm();

  PACKB(0, w2);
  __builtin_amdgcn_sched_barrier(0);
  MFMA_STEP(1, 1);
  bar_lgkm();

  PACKB(1, w0);
  __builtin_amdgcn_sched_barrier(0);
  MFMA_STEP(2, 0);
  bar_lgkm();

  MFMA_STEP(3, 1);

  // ---- epilogue: stage u rows through A-region (32KB = 128 rows x 256B)
  bar_lgkm();                                // all MFMA ds_reads of A done
#pragma unroll
  for (int mf = 0; mf < 4; ++mf) {
#pragma unroll
    for (int nf = 0; nf < 2; ++nf) {
      int col = wn * 32 + nf * 16 + (lane & 15);
#pragma unroll
      for (int j = 0; j < 4; ++j) {
        int rr = wm * 64 + mf * 16 + (lane >> 4) * 4 + j;
        int byte = (rr * 256 + col * 2) ^ ((rr & 7) << 4);
        *reinterpret_cast<ushort*>(Alds + byte) = f2bf(acc[mf][nf][j]);
      }
    }
  }
  bar_lgkm();
#pragma unroll
  for (int ci = 0; ci < 4; ++ci) {
    int c = t + ci * 512;                    // 2048 x 16B chunks = 32KB
    int rowl = c >> 4;
    int cb = (c & 15) * 16;
    int sbyte = (rowl * 256 + cb) ^ ((rowl & 7) << 4);
    uint4 v = *reinterpret_cast<uint4*>(Alds + sbyte);
    *reinterpret_cast<uint4*>(ub + (size_t)rowl * 524288 + cb / 2) = v;
  }
#undef LOADW
#undef PACKB
#undef MFMA_STEP
}

// ---------------- K2: s = sum_n0 u ; logits = (u . s)/sqrt(128)
// Grid reversed: reads the u K1 wrote last first (L3-resident).
__global__ __launch_bounds__(256) void k2_logits(
    const ushort* __restrict__ u, float* __restrict__ logits)
{
  const int bid = gridDim.x - 1 - blockIdx.x;  // b*64 + n1, reversed
  const ushort* up = u + (size_t)bid * 8192;   // [n0][d1] 64x128
  const int t = threadIdx.x;

  __shared__ float part[8][128];
  __shared__ float sS[128];
  __shared__ float part2[256];

  {
    int d4 = (t & 31) * 4;
    int g = t >> 5;                     // n0 group of 8
    float4 a = {0, 0, 0, 0};
    for (int n0 = g * 8; n0 < g * 8 + 8; ++n0) {
      ushort4 v = *reinterpret_cast<const ushort4*>(up + n0 * 128 + d4);
      a.x += bf2f(v.x); a.y += bf2f(v.y); a.z += bf2f(v.z); a.w += bf2f(v.w);
    }
    *reinterpret_cast<float4*>(&part[g][d4]) = a;
  }
  __syncthreads();
  if (t < 128) {
    float s = 0;
#pragma unroll
    for (int g = 0; g < 8; ++g) s += part[g][t];
    sS[t] = s;
  }
  __syncthreads();
  {
    int n0 = t >> 2, qq = t & 3;
    float acc = 0;
#pragma unroll
    for (int j = 0; j < 32; j += 4) {
      int d = qq * 32 + j;
      ushort4 v = *reinterpret_cast<const ushort4*>(up + n0 * 128 + d);
      acc += bf2f(v.x) * sS[d] + bf2f(v.y) * sS[d + 1] + bf2f(v.z) * sS[d + 2] + bf2f(v.w) * sS[d + 3];
    }
    part2[t] = acc;
  }
  __syncthreads();
  if (t < 64) {
    float l = (part2[t * 4] + part2[t * 4 + 1] + part2[t * 4 + 2] + part2[t * 4 + 3]) * 0.08838834764831845f;
    logits[(size_t)bid * 64 + t] = l;
  }
}

// ---------------- K3: softmax over n1 (per (b,n0)) + bias
__global__ __launch_bounds__(64) void k3_softmax(
    const float* __restrict__ logits, const float* __restrict__ bias,
    float* __restrict__ cc)
{
  const int b = blockIdx.x;
  const int t = threadIdx.x;            // = n0
  __shared__ float L[64][64];           // [n1][n0]
  const float* lp = logits + (size_t)b * 4096;
  for (int i = 0; i < 64; ++i) L[i][t] = lp[i * 64 + t];
  __syncthreads();
  float m = -1e30f;
#pragma unroll
  for (int n1 = 0; n1 < 64; ++n1) m = fmaxf(m, L[n1][t]);
  float sum = 0.f;
#pragma unroll
  for (int n1 = 0; n1 < 64; ++n1) {
    float e = __expf(L[n1][t] - m);
    L[n1][t] = e;
    sum += e;
  }
  float inv = 1.0f / sum;
  float* cp = cc + (size_t)b * 4096;
  for (int n1 = 0; n1 < 64; ++n1)
    cp[n1 * 64 + t] = L[n1][t] * inv + bias[n1 * 64 + t];
}

// ---------------- K4: out[b,n1,d1] = sum_n0 u * c
__global__ __launch_bounds__(128) void k4_out(
    const ushort* __restrict__ u, const float* __restrict__ cc,
    float* __restrict__ out)
{
  const int bid = blockIdx.x;           // b*64 + n1
  const ushort* up = u + (size_t)bid * 8192;
  const int t = threadIdx.x;
  __shared__ float cL[64];
  __shared__ float part[4][128];
  if (t < 64) cL[t] = cc[(size_t)bid * 64 + t];
  __syncthreads();
  int d4 = (t & 31) * 4, g = t >> 5;    // g: n0 group of 16
  float4 a = {0, 0, 0, 0};
  for (int n0 = g * 16; n0 < g * 16 + 16; ++n0) {
    ushort4 v = *reinterpret_cast<const ushort4*>(up + n0 * 128 + d4);
    float c = cL[n0];
    a.x += bf2f(v.x) * c; a.y += bf2f(v.y) * c; a.z += bf2f(v.z) * c; a.w += bf2f(v.w) * c;
  }
  *reinterpret_cast<float4*>(&part[g][d4]) = a;
  __syncthreads();
  if (t < 128) {
    float r = part[0][t] + part[1][t] + part[2][t] + part[3][t];
    __builtin_nontemporal_store(r, &out[(size_t)bid * 128 + t]);
  }
}

extern "C" void kernel_launch(void* const* d_in, const int* in_sizes, int n_in,
                              void* d_out, int out_size, void* d_ws, size_t ws_size,
                              hipStream_t stream) {
  const float* x = (const float*)d_in[0];
  const float* W = (const float*)d_in[1];
  const float* bias = (const float*)d_in[2];
  float* out = (float*)d_out;

  ushort* u = (ushort*)d_ws;                                   // 268435456 B
  float* logits = (float*)((char*)d_ws + 268435456u);          // 4194304 B
  char* ccxbf = (char*)d_ws + 272629760u;                      // 4194304 B shared
  ushort* xbf = (ushort*)ccxbf;     // live Px..K1
  float* cc = (float*)ccxbf;        // live K3..K4 (overwrites xbf after K1 done)

  hipLaunchKernelGGL(px_cvt,     dim3(1024),     dim3(512), 0, stream, x, xbf);
  hipLaunchKernelGGL(k1_gemm,    dim3(8192),     dim3(512), 0, stream, xbf, W, u);
  hipLaunchKernelGGL(k2_logits,  dim3(BB * NN1), dim3(256), 0, stream, u, logits);
  hipLaunchKernelGGL(k3_softmax, dim3(BB),       dim3(64),  0, stream, logits, bias, cc);
  hipLaunchKernelGGL(k4_out,     dim3(BB * NN1), dim3(128), 0, stream, u, cc, out);
}

// Round 10
// 192.728 us; speedup vs baseline: 1.0637x; 1.0115x over previous
//
#include <hip/hip_runtime.h>
#include <hip/hip_bf16.h>
#include <cstdint>

// Problem: B=256, N0=64, D0=128, N1=64, D1=128 (all fp32 in/out).
// u[b,n1,n0,d1] = sum_d0 x[b,n0,d0]*W[n1,n0,d0,d1]
// s = sum_n0 u ; logit = (u . s)/sqrt(128) ; c = softmax_n1(logit) + bias
// out[b,n1,d1] = sum_n0 u*c
//
// ws layout: u bf16 [B][N1][N0][D1]      @ 0          (268435456 B)
//            logits f32 [B][N1][N0]      @ 268435456  (4194304 B)
//            cc/xbf shared region        @ 272629760  (4194304 B)
//
// RULES: (R4/R5) unified VGPR+AGPR <= 128/wave. (R8/R9) W streamed
// nontemporal (L3 kept for u). (R10) one block per (n1,n0) reads W ONCE —
// W HBM = 268 MB structural, not L2-reuse-dependent.

#define BB 256
#define NN0 64
#define DD0 128
#define NN1 64
#define DD1 128

typedef __attribute__((ext_vector_type(8))) short bf16x8;
typedef __attribute__((ext_vector_type(4))) float f32x4;
typedef __attribute__((ext_vector_type(4))) ushort u16x4;

__device__ __forceinline__ ushort f2bf(float f) {
  uint32_t b = __float_as_uint(f);
  b += 0x7FFFu + ((b >> 16) & 1u);      // RNE
  return (ushort)(b >> 16);
}
__device__ __forceinline__ float bf2f(ushort h) {
  return __uint_as_float(((uint32_t)h) << 16);
}

__device__ __forceinline__ void gld_lds16(const void* g, void* l) {
  __builtin_amdgcn_global_load_lds(
      (const __attribute__((address_space(1))) void*)g,
      (__attribute__((address_space(3))) void*)l, 16, 0, 0);
}

// barrier that does NOT drain vmcnt (W prefetch stays in flight across it).
__device__ __forceinline__ void bar_lgkm() {
  asm volatile("s_waitcnt lgkmcnt(0)" ::: "memory");
  __builtin_amdgcn_s_barrier();
  __builtin_amdgcn_sched_barrier(0);
}

// ---------------- Px: x fp32 -> bf16 (x read is single-use: nontemporal)
__global__ __launch_bounds__(512) void px_cvt(
    const float* __restrict__ x, ushort* __restrict__ xbf)
{
  int i = blockIdx.x * 512 + threadIdx.x;   // 524288 f32x4 chunks total
  const f32x4* src = reinterpret_cast<const f32x4*>(x) + i;
  f32x4 v = __builtin_nontemporal_load(src);
  ushort4 h;
  h.x = f2bf(v.x); h.y = f2bf(v.y); h.z = f2bf(v.z); h.w = f2bf(v.w);
  *reinterpret_cast<ushort4*>(xbf + (size_t)i * 4) = h;
}

// ---------------- K1: block = (n1, n0). M=256(b) x N=128(d1), K=128.
// A = x[:,n0,:] staged ONCE via global_load_lds (64KB). W (64KB) read ONCE,
// nontemporal, depth-2 reg pipeline through dbuf B-LDS, 4 k-steps of 32.
// lgkm-only barriers keep W loads in flight. LDS: A 64K + B 8K*2 = 80KB ->
// exactly 2 blocks/CU (160KB). 8 waves = 4 M x 2 N, wave-tile 64x64.
__global__ __launch_bounds__(512, 4) void k1_gemm(
    const ushort* __restrict__ xbf, const float* __restrict__ W,
    ushort* __restrict__ u)
{
  __shared__ __align__(16) char lds[81920];
  char* Alds = lds;                          // 256 rows(b) x 256B (k=128), XOR-swz
  char* Bl[2] = { lds + 65536, lds + 73728 };// 128 rows(d1) x 64B (32 k), swz

  // XCD-chunk: 4096 blocks = 8 XCDs x 512; XCD owns n0 in [x*8,x*8+8).
  // Sequential locals share n0 -> x-slice L2-resident across 64 n1 blocks.
  const int q = blockIdx.x;
  const int local = q >> 3;
  const int n0 = (q & 7) * 8 + (local >> 6);
  const int n1 = local & 63;
  const int t = threadIdx.x;
  const int lane = t & 63, wave = t >> 6;
  const int wm = wave >> 1, wn = wave & 1;   // 4 M-waves(64b) x 2 N-waves(64 d1)

  const ushort* xb = xbf + n0 * DD0;                            // + row*8192 + d0
  const float* Wb = W + ((size_t)n1 * NN0 + n0) * (DD0 * DD1);  // [d0][d1]
  ushort* ub = u + ((size_t)n1 * 8192 + (size_t)n0 * 128);      // + b*524288 + d1

  f32x4 acc[4][4];
#pragma unroll
  for (int a = 0; a < 4; ++a)
#pragma unroll
    for (int b = 0; b < 4; ++b) acc[a][b] = {0.f, 0.f, 0.f, 0.f};

  // W gather: one 16B chunk per thread: d1 = t&127, kc = t>>7 (8 k's)
  const int gd1 = t & 127, gkc = t >> 7;
  const int bbyte = (gd1 * 64 + gkc * 16) ^ ((gd1 & 3) << 4) ^ (((gd1 >> 2) & 1) << 6);
  float w0[8], w1[8];

#define LOADW(hh, ks)                                                         \
  {                                                                           \
    _Pragma("unroll")                                                         \
    for (int j = 0; j < 8; ++j)                                               \
      hh[j] = __builtin_nontemporal_load(                                     \
          Wb + (size_t)((ks) * 32 + gkc * 8 + j) * 128 + gd1);                \
  }
#define PACKB(bi, hh)                                                         \
  {                                                                           \
    uint32_t p0 = (uint32_t)f2bf(hh[0]) | ((uint32_t)f2bf(hh[1]) << 16);      \
    uint32_t p1 = (uint32_t)f2bf(hh[2]) | ((uint32_t)f2bf(hh[3]) << 16);      \
    uint32_t p2 = (uint32_t)f2bf(hh[4]) | ((uint32_t)f2bf(hh[5]) << 16);      \
    uint32_t p3 = (uint32_t)f2bf(hh[6]) | ((uint32_t)f2bf(hh[7]) << 16);      \
    *reinterpret_cast<uint4*>(Bl[bi] + bbyte) = make_uint4(p0, p1, p2, p3);   \
  }
#define MFMA_STEP(ks, bi)                                                     \
  {                                                                           \
    const int kb16 = (lane >> 4);                                             \
    const int ka = (ks) * 32 + kb16 * 8;                                      \
    bf16x8 af[4], bfr[4];                                                     \
    _Pragma("unroll")                                                         \
    for (int mf = 0; mf < 4; ++mf) {                                          \
      int row = wm * 64 + mf * 16 + (lane & 15);                              \
      int byte = (row * 256 + ka * 2) ^ ((row & 7) << 4);                     \
      af[mf] = *reinterpret_cast<const bf16x8*>(Alds + byte);                 \
    }                                                                         \
    _Pragma("unroll")                                                         \
    for (int nf = 0; nf < 4; ++nf) {                                          \
      int n = wn * 64 + nf * 16 + (lane & 15);                                \
      int byte = (n * 64 + kb16 * 16) ^ ((n & 3) << 4) ^ (((n >> 2) & 1) << 6); \
      bfr[nf] = *reinterpret_cast<const bf16x8*>(Bl[bi] + byte);              \
    }                                                                         \
    _Pragma("unroll")                                                         \
    for (int mf = 0; mf < 4; ++mf)                                            \
      _Pragma("unroll")                                                       \
      for (int nf = 0; nf < 4; ++nf)                                          \
        acc[mf][nf] = __builtin_amdgcn_mfma_f32_16x16x32_bf16(af[mf], bfr[nf], acc[mf][nf], 0, 0, 0); \
  }

  // ---- prologue. Issue order: A-DMA oldest, then W0,W1 (depth-2 pipeline).
#pragma unroll
  for (int s = 0; s < 8; ++s) {
    int seg = wave * 8 + s;                  // 64 segs x 1024B (4 rows of 256B)
    int row = seg * 4 + (lane >> 4);
    int srcc = (lane & 15) ^ (row & 7);      // source pre-swizzle (linear dest)
    gld_lds16(xb + (size_t)row * 8192 + srcc * 8, Alds + seg * 1024);
  }
  __builtin_amdgcn_sched_barrier(0);
  LOADW(w0, 0);
  __builtin_amdgcn_sched_barrier(0);
  LOADW(w1, 1);
  __builtin_amdgcn_sched_barrier(0);
  PACKB(0, w0);                              // waits w0 (and A-DMA, older); w1 flies
  LOADW(w0, 2);                              // k2 in flight across barrier
  __builtin_amdgcn_sched_barrier(0);
  bar_lgkm();

  // ---- 4 k-steps, one lgkm-barrier each; no vmcnt drain in the loop.
  PACKB(1, w1);                              // waits w1; w2 flies
  LOADW(w1, 3);                              // k3 in flight
  __builtin_amdgcn_sched_barrier(0);
  MFMA_STEP(0, 0);
  bar_lgkm();

  PACKB(0, w0);                              // waits w2; w3 flies
  __builtin_amdgcn_sched_barrier(0);
  MFMA_STEP(1, 1);
  bar_lgkm();

  PACKB(1, w1);                              // waits w3
  __builtin_amdgcn_sched_barrier(0);
  MFMA_STEP(2, 0);
  bar_lgkm();

  MFMA_STEP(3, 1);

  // ---- epilogue: stage u rows through A-region (64KB = 256 rows x 256B)
  bar_lgkm();                                // all MFMA ds_reads of A done
#pragma unroll
  for (int mf = 0; mf < 4; ++mf) {
#pragma unroll
    for (int nf = 0; nf < 4; ++nf) {
      int col = wn * 64 + nf * 16 + (lane & 15);
#pragma unroll
      for (int j = 0; j < 4; ++j) {
        int rr = wm * 64 + mf * 16 + (lane >> 4) * 4 + j;
        int byte = (rr * 256 + col * 2) ^ ((rr & 7) << 4);
        *reinterpret_cast<ushort*>(Alds + byte) = f2bf(acc[mf][nf][j]);
      }
    }
  }
  bar_lgkm();
#pragma unroll
  for (int ci = 0; ci < 8; ++ci) {
    int c = t + ci * 512;                    // 4096 x 16B chunks = 64KB
    int rowl = c >> 4;
    int cb = (c & 15) * 16;
    int sbyte = (rowl * 256 + cb) ^ ((rowl & 7) << 4);
    uint4 v = *reinterpret_cast<uint4*>(Alds + sbyte);
    *reinterpret_cast<uint4*>(ub + (size_t)rowl * 524288 + cb / 2) = v;
  }
#undef LOADW
#undef PACKB
#undef MFMA_STEP
}

// ---------------- K2: s = sum_n0 u ; logits = (u . s)/sqrt(128)
// Grid reversed: reads the u K1 wrote last first (L3-resident). Normal loads
// (keep u in L3 for K4).
__global__ __launch_bounds__(256) void k2_logits(
    const ushort* __restrict__ u, float* __restrict__ logits)
{
  const int bid = gridDim.x - 1 - blockIdx.x;  // b*64 + n1, reversed
  const ushort* up = u + (size_t)bid * 8192;   // [n0][d1] 64x128
  const int t = threadIdx.x;

  __shared__ float part[8][128];
  __shared__ float sS[128];
  __shared__ float part2[256];

  {
    int d4 = (t & 31) * 4;
    int g = t >> 5;                     // n0 group of 8
    float4 a = {0, 0, 0, 0};
    for (int n0 = g * 8; n0 < g * 8 + 8; ++n0) {
      ushort4 v = *reinterpret_cast<const ushort4*>(up + n0 * 128 + d4);
      a.x += bf2f(v.x); a.y += bf2f(v.y); a.z += bf2f(v.z); a.w += bf2f(v.w);
    }
    *reinterpret_cast<float4*>(&part[g][d4]) = a;
  }
  __syncthreads();
  if (t < 128) {
    float s = 0;
#pragma unroll
    for (int g = 0; g < 8; ++g) s += part[g][t];
    sS[t] = s;
  }
  __syncthreads();
  {
    int n0 = t >> 2, qq = t & 3;
    float acc = 0;
#pragma unroll
    for (int j = 0; j < 32; j += 4) {
      int d = qq * 32 + j;
      ushort4 v = *reinterpret_cast<const ushort4*>(up + n0 * 128 + d);
      acc += bf2f(v.x) * sS[d] + bf2f(v.y) * sS[d + 1] + bf2f(v.z) * sS[d + 2] + bf2f(v.w) * sS[d + 3];
    }
    part2[t] = acc;
  }
  __syncthreads();
  if (t < 64) {
    float l = (part2[t * 4] + part2[t * 4 + 1] + part2[t * 4 + 2] + part2[t * 4 + 3]) * 0.08838834764831845f;
    logits[(size_t)bid * 64 + t] = l;
  }
}

// ---------------- K3: softmax over n1 (per (b,n0)) + bias
__global__ __launch_bounds__(64) void k3_softmax(
    const float* __restrict__ logits, const float* __restrict__ bias,
    float* __restrict__ cc)
{
  const int b = blockIdx.x;
  const int t = threadIdx.x;            // = n0
  __shared__ float L[64][64];           // [n1][n0]
  const float* lp = logits + (size_t)b * 4096;
  for (int i = 0; i < 64; ++i) L[i][t] = lp[i * 64 + t];
  __syncthreads();
  float m = -1e30f;
#pragma unroll
  for (int n1 = 0; n1 < 64; ++n1) m = fmaxf(m, L[n1][t]);
  float sum = 0.f;
#pragma unroll
  for (int n1 = 0; n1 < 64; ++n1) {
    float e = __expf(L[n1][t] - m);
    L[n1][t] = e;
    sum += e;
  }
  float inv = 1.0f / sum;
  float* cp = cc + (size_t)b * 4096;
  for (int n1 = 0; n1 < 64; ++n1)
    cp[n1 * 64 + t] = L[n1][t] * inv + bias[n1 * 64 + t];
}

// ---------------- K4: out[b,n1,d1] = sum_n0 u * c (u loads nt: last reader)
__global__ __launch_bounds__(128) void k4_out(
    const ushort* __restrict__ u, const float* __restrict__ cc,
    float* __restrict__ out)
{
  const int bid = blockIdx.x;           // b*64 + n1
  const ushort* up = u + (size_t)bid * 8192;
  const int t = threadIdx.x;
  __shared__ float cL[64];
  __shared__ float part[4][128];
  if (t < 64) cL[t] = cc[(size_t)bid * 64 + t];
  __syncthreads();
  int d4 = (t & 31) * 4, g = t >> 5;    // g: n0 group of 16
  float4 a = {0, 0, 0, 0};
  for (int n0 = g * 16; n0 < g * 16 + 16; ++n0) {
    u16x4 v = __builtin_nontemporal_load(
        reinterpret_cast<const u16x4*>(up + n0 * 128 + d4));
    float c = cL[n0];
    a.x += bf2f(v.x) * c; a.y += bf2f(v.y) * c; a.z += bf2f(v.z) * c; a.w += bf2f(v.w) * c;
  }
  *reinterpret_cast<float4*>(&part[g][d4]) = a;
  __syncthreads();
  if (t < 128) {
    float r = part[0][t] + part[1][t] + part[2][t] + part[3][t];
    __builtin_nontemporal_store(r, &out[(size_t)bid * 128 + t]);
  }
}

extern "C" void kernel_launch(void* const* d_in, const int* in_sizes, int n_in,
                              void* d_out, int out_size, void* d_ws, size_t ws_size,
                              hipStream_t stream) {
  const float* x = (const float*)d_in[0];
  const float* W = (const float*)d_in[1];
  const float* bias = (const float*)d_in[2];
  float* out = (float*)d_out;

  ushort* u = (ushort*)d_ws;                                   // 268435456 B
  float* logits = (float*)((char*)d_ws + 268435456u);          // 4194304 B
  char* ccxbf = (char*)d_ws + 272629760u;                      // 4194304 B shared
  ushort* xbf = (ushort*)ccxbf;     // live Px..K1
  float* cc = (float*)ccxbf;        // live K3..K4 (overwrites xbf after K1 done)

  hipLaunchKernelGGL(px_cvt,     dim3(1024),     dim3(512), 0, stream, x, xbf);
  hipLaunchKernelGGL(k1_gemm,    dim3(4096),     dim3(512), 0, stream, xbf, W, u);
  hipLaunchKernelGGL(k2_logits,  dim3(BB * NN1), dim3(256), 0, stream, u, logits);
  hipLaunchKernelGGL(k3_softmax, dim3(BB),       dim3(64),  0, stream, logits, bias, cc);
  hipLaunchKernelGGL(k4_out,     dim3(BB * NN1), dim3(128), 0, stream, u, cc, out);
}

// Round 11
// 183.074 us; speedup vs baseline: 1.1198x; 1.0527x over previous
//
#include <hip/hip_runtime.h>
#include <hip/hip_bf16.h>
#include <cstdint>

// Problem: B=256, N0=64, D0=128, N1=64, D1=128 (all fp32 in/out).
// u[b,n1,n0,d1] = sum_d0 x[b,n0,d0]*W[n1,n0,d0,d1]
// s = sum_n0 u ; logit = (u . s)/sqrt(128) ; c = softmax_n1(logit) + bias
// out[b,n1,d1] = sum_n0 u*c
//
// ws layout: u bf16 [B][N1][N0][D1] @ 0 (268435456 B); xbf @ 268435456 (4 MB)
//
// RULES: (R4/R5) unified VGPR+AGPR <= 128/wave in k1. (R8/R9) W nontemporal
// (keep L3 for u). (R10) W read once structurally. (R11) K2/K3/K4 fused per-b:
// u read from HBM once; passes 2/3 come from L2/L3.

#define BB 256
#define NN0 64
#define DD0 128
#define NN1 64
#define DD1 128

typedef __attribute__((ext_vector_type(8))) short bf16x8;
typedef __attribute__((ext_vector_type(4))) float f32x4;

__device__ __forceinline__ ushort f2bf(float f) {
  uint32_t b = __float_as_uint(f);
  b += 0x7FFFu + ((b >> 16) & 1u);      // RNE
  return (ushort)(b >> 16);
}
__device__ __forceinline__ float bf2f(ushort h) {
  return __uint_as_float(((uint32_t)h) << 16);
}

__device__ __forceinline__ void gld_lds16(const void* g, void* l) {
  __builtin_amdgcn_global_load_lds(
      (const __attribute__((address_space(1))) void*)g,
      (__attribute__((address_space(3))) void*)l, 16, 0, 0);
}

__device__ __forceinline__ void bar_lgkm() {
  asm volatile("s_waitcnt lgkmcnt(0)" ::: "memory");
  __builtin_amdgcn_s_barrier();
  __builtin_amdgcn_sched_barrier(0);
}

// ---------------- Px: x fp32 -> bf16 (single-use read: nontemporal)
__global__ __launch_bounds__(512) void px_cvt(
    const float* __restrict__ x, ushort* __restrict__ xbf)
{
  int i = blockIdx.x * 512 + threadIdx.x;
  const f32x4* src = reinterpret_cast<const f32x4*>(x) + i;
  f32x4 v = __builtin_nontemporal_load(src);
  ushort4 h;
  h.x = f2bf(v.x); h.y = f2bf(v.y); h.z = f2bf(v.z); h.w = f2bf(v.w);
  *reinterpret_cast<ushort4*>(xbf + (size_t)i * 4) = h;
}

// ---------------- K1: block = (n1, n0). M=256(b) x N=128(d1), K=128.
// (unchanged from R10: A staged once via global_load_lds, W read once nt,
// depth-2 reg pipeline, lgkm-only barriers; LDS 80KB -> 2 blocks/CU.)
__global__ __launch_bounds__(512, 4) void k1_gemm(
    const ushort* __restrict__ xbf, const float* __restrict__ W,
    ushort* __restrict__ u)
{
  __shared__ __align__(16) char lds[81920];
  char* Alds = lds;                          // 256 rows(b) x 256B (k=128), XOR-swz
  char* Bl[2] = { lds + 65536, lds + 73728 };// 128 rows(d1) x 64B (32 k), swz

  const int q = blockIdx.x;
  const int local = q >> 3;
  const int n0 = (q & 7) * 8 + (local >> 6);
  const int n1 = local & 63;
  const int t = threadIdx.x;
  const int lane = t & 63, wave = t >> 6;
  const int wm = wave >> 1, wn = wave & 1;   // 4 M-waves(64b) x 2 N-waves(64 d1)

  const ushort* xb = xbf + n0 * DD0;
  const float* Wb = W + ((size_t)n1 * NN0 + n0) * (DD0 * DD1);
  ushort* ub = u + ((size_t)n1 * 8192 + (size_t)n0 * 128);

  f32x4 acc[4][4];
#pragma unroll
  for (int a = 0; a < 4; ++a)
#pragma unroll
    for (int b = 0; b < 4; ++b) acc[a][b] = {0.f, 0.f, 0.f, 0.f};

  const int gd1 = t & 127, gkc = t >> 7;
  const int bbyte = (gd1 * 64 + gkc * 16) ^ ((gd1 & 3) << 4) ^ (((gd1 >> 2) & 1) << 6);
  float w0[8], w1[8];

#define LOADW(hh, ks)                                                         \
  {                                                                           \
    _Pragma("unroll")                                                         \
    for (int j = 0; j < 8; ++j)                                               \
      hh[j] = __builtin_nontemporal_load(                                     \
          Wb + (size_t)((ks) * 32 + gkc * 8 + j) * 128 + gd1);                \
  }
#define PACKB(bi, hh)                                                         \
  {                                                                           \
    uint32_t p0 = (uint32_t)f2bf(hh[0]) | ((uint32_t)f2bf(hh[1]) << 16);      \
    uint32_t p1 = (uint32_t)f2bf(hh[2]) | ((uint32_t)f2bf(hh[3]) << 16);      \
    uint32_t p2 = (uint32_t)f2bf(hh[4]) | ((uint32_t)f2bf(hh[5]) << 16);      \
    uint32_t p3 = (uint32_t)f2bf(hh[6]) | ((uint32_t)f2bf(hh[7]) << 16);      \
    *reinterpret_cast<uint4*>(Bl[bi] + bbyte) = make_uint4(p0, p1, p2, p3);   \
  }
#define MFMA_STEP(ks, bi)                                                     \
  {                                                                           \
    const int kb16 = (lane >> 4);                                             \
    const int ka = (ks) * 32 + kb16 * 8;                                      \
    bf16x8 af[4], bfr[4];                                                     \
    _Pragma("unroll")                                                         \
    for (int mf = 0; mf < 4; ++mf) {                                          \
      int row = wm * 64 + mf * 16 + (lane & 15);                              \
      int byte = (row * 256 + ka * 2) ^ ((row & 7) << 4);                     \
      af[mf] = *reinterpret_cast<const bf16x8*>(Alds + byte);                 \
    }                                                                         \
    _Pragma("unroll")                                                         \
    for (int nf = 0; nf < 4; ++nf) {                                          \
      int n = wn * 64 + nf * 16 + (lane & 15);                                \
      int byte = (n * 64 + kb16 * 16) ^ ((n & 3) << 4) ^ (((n >> 2) & 1) << 6); \
      bfr[nf] = *reinterpret_cast<const bf16x8*>(Bl[bi] + byte);              \
    }                                                                         \
    _Pragma("unroll")                                                         \
    for (int mf = 0; mf < 4; ++mf)                                            \
      _Pragma("unroll")                                                       \
      for (int nf = 0; nf < 4; ++nf)                                          \
        acc[mf][nf] = __builtin_amdgcn_mfma_f32_16x16x32_bf16(af[mf], bfr[nf], acc[mf][nf], 0, 0, 0); \
  }

#pragma unroll
  for (int s = 0; s < 8; ++s) {
    int seg = wave * 8 + s;
    int row = seg * 4 + (lane >> 4);
    int srcc = (lane & 15) ^ (row & 7);
    gld_lds16(xb + (size_t)row * 8192 + srcc * 8, Alds + seg * 1024);
  }
  __builtin_amdgcn_sched_barrier(0);
  LOADW(w0, 0);
  __builtin_amdgcn_sched_barrier(0);
  LOADW(w1, 1);
  __builtin_amdgcn_sched_barrier(0);
  PACKB(0, w0);
  LOADW(w0, 2);
  __builtin_amdgcn_sched_barrier(0);
  bar_lgkm();

  PACKB(1, w1);
  LOADW(w1, 3);
  __builtin_amdgcn_sched_barrier(0);
  MFMA_STEP(0, 0);
  bar_lgkm();

  PACKB(0, w0);
  __builtin_amdgcn_sched_barrier(0);
  MFMA_STEP(1, 1);
  bar_lgkm();

  PACKB(1, w1);
  __builtin_amdgcn_sched_barrier(0);
  MFMA_STEP(2, 0);
  bar_lgkm();

  MFMA_STEP(3, 1);

  bar_lgkm();
#pragma unroll
  for (int mf = 0; mf < 4; ++mf) {
#pragma unroll
    for (int nf = 0; nf < 4; ++nf) {
      int col = wn * 64 + nf * 16 + (lane & 15);
#pragma unroll
      for (int j = 0; j < 4; ++j) {
        int rr = wm * 64 + mf * 16 + (lane >> 4) * 4 + j;
        int byte = (rr * 256 + col * 2) ^ ((rr & 7) << 4);
        *reinterpret_cast<ushort*>(Alds + byte) = f2bf(acc[mf][nf][j]);
      }
    }
  }
  bar_lgkm();
#pragma unroll
  for (int ci = 0; ci < 8; ++ci) {
    int c = t + ci * 512;
    int rowl = c >> 4;
    int cb = (c & 15) * 16;
    int sbyte = (rowl * 256 + cb) ^ ((rowl & 7) << 4);
    uint4 v = *reinterpret_cast<uint4*>(Alds + sbyte);
    *reinterpret_cast<uint4*>(ub + (size_t)rowl * 524288 + cb / 2) = v;
  }
#undef LOADW
#undef PACKB
#undef MFMA_STEP
}

// ---------------- K234 fused: block = b. 8 waves; wave w owns n1 in [8w,8w+8).
// A: s[d1-pair] per lane over n0 (HBM read). B: re-read rows (L2-hot),
// butterfly transpose-reduce -> logits. C: parallel softmax over n1 + bias.
// D: out = sum_n0 c*u (u from L3/L2).
__global__ __launch_bounds__(512, 1) void k234_fused(
    const ushort* __restrict__ u, const float* __restrict__ bias,
    float* __restrict__ out)
{
  const int b = blockIdx.x;
  const ushort* ub = u + (size_t)b * 524288;      // [n1][n0][d1]
  const int t = threadIdx.x;
  const int lane = t & 63, w = t >> 6;

  __shared__ float cL[64][65];                    // logits -> c (padded)
  __shared__ float red[2][8][64];                 // phase-C partials

  // ---- Phases A+B per n1
#pragma unroll 1
  for (int i = 0; i < 8; ++i) {
    const int n1 = w * 8 + i;
    const ushort* row = ub + n1 * 8192 + lane * 2;  // + n0*128
    float s0 = 0.f, s1 = 0.f;
#pragma unroll
    for (int n0 = 0; n0 < 64; ++n0) {
      uint32_t v = *reinterpret_cast<const uint32_t*>(row + n0 * 128);
      s0 += bf2f((ushort)(v & 0xffff));
      s1 += bf2f((ushort)(v >> 16));
    }
    // B: per-lane partial dot for each n0 (rows are L2-hot)
    float p[64];
#pragma unroll
    for (int n0 = 0; n0 < 64; ++n0) {
      uint32_t v = *reinterpret_cast<const uint32_t*>(row + n0 * 128);
      p[n0] = bf2f((ushort)(v & 0xffff)) * s0 + bf2f((ushort)(v >> 16)) * s1;
    }
    // butterfly transpose-reduce: lane l ends with full dot for n0 = l
#pragma unroll
    for (int s2 = 0; s2 < 6; ++s2) {
      const int kb = (lane >> s2) & 1;
#pragma unroll
      for (int j = 0; j < (64 >> (s2 + 1)); ++j) {
        float a = p[2 * j], b2 = p[2 * j + 1];
        float mine = kb ? b2 : a;
        float send = kb ? a : b2;
        p[j] = mine + __shfl_xor(send, 1 << s2, 64);
      }
    }
    cL[n1][lane] = p[0] * 0.08838834764831845f;   // /sqrt(128)
  }
  __syncthreads();

  // ---- Phase C: softmax over n1 (per n0) + bias; 8 groups of 8 n1
  {
    const int g = t >> 6, n0 = t & 63;
    float pm = -1e30f;
#pragma unroll
    for (int j = 0; j < 8; ++j) pm = fmaxf(pm, cL[g * 8 + j][n0]);
    red[0][g][n0] = pm;
    __syncthreads();
    if (g == 0) {
      float m = red[0][0][n0];
#pragma unroll
      for (int j = 1; j < 8; ++j) m = fmaxf(m, red[0][j][n0]);
      red[0][0][n0] = m;
    }
    __syncthreads();
    const float m = red[0][0][n0];
    float ps = 0.f;
#pragma unroll
    for (int j = 0; j < 8; ++j) {
      float e = __expf(cL[g * 8 + j][n0] - m);
      cL[g * 8 + j][n0] = e;
      ps += e;
    }
    red[1][g][n0] = ps;
    __syncthreads();
    if (g == 0) {
      float sm = 0.f;
#pragma unroll
      for (int j = 0; j < 8; ++j) sm += red[1][j][n0];
      red[1][0][n0] = 1.0f / sm;
    }
    __syncthreads();
    const float inv = red[1][0][n0];
#pragma unroll
    for (int j = 0; j < 8; ++j) {
      int n1 = g * 8 + j;
      cL[n1][n0] = cL[n1][n0] * inv + bias[n1 * 64 + n0];
    }
  }
  __syncthreads();

  // ---- Phase D: out[n1][d1] = sum_n0 c[n1][n0] * u[n1][n0][d1]
#pragma unroll 1
  for (int i = 0; i < 8; ++i) {
    const int n1 = w * 8 + i;
    const ushort* row = ub + n1 * 8192 + lane * 2;
    float o0 = 0.f, o1 = 0.f;
#pragma unroll
    for (int n0 = 0; n0 < 64; ++n0) {
      uint32_t v = *reinterpret_cast<const uint32_t*>(row + n0 * 128);
      float c = cL[n1][n0];
      o0 += bf2f((ushort)(v & 0xffff)) * c;
      o1 += bf2f((ushort)(v >> 16)) * c;
    }
    float2 o = make_float2(o0, o1);
    *reinterpret_cast<float2*>(out + (size_t)b * 8192 + n1 * 128 + lane * 2) = o;
  }
}

extern "C" void kernel_launch(void* const* d_in, const int* in_sizes, int n_in,
                              void* d_out, int out_size, void* d_ws, size_t ws_size,
                              hipStream_t stream) {
  const float* x = (const float*)d_in[0];
  const float* W = (const float*)d_in[1];
  const float* bias = (const float*)d_in[2];
  float* out = (float*)d_out;

  ushort* u = (ushort*)d_ws;                            // 268435456 B
  ushort* xbf = (ushort*)((char*)d_ws + 268435456u);    // 4194304 B

  hipLaunchKernelGGL(px_cvt,     dim3(1024), dim3(512), 0, stream, x, xbf);
  hipLaunchKernelGGL(k1_gemm,    dim3(4096), dim3(512), 0, stream, xbf, W, u);
  hipLaunchKernelGGL(k234_fused, dim3(BB),   dim3(512), 0, stream, u, bias, out);
}

// Round 12
// 180.915 us; speedup vs baseline: 1.1331x; 1.0119x over previous
//
#include <hip/hip_runtime.h>
#include <hip/hip_bf16.h>
#include <cstdint>

// Problem: B=256, N0=64, D0=128, N1=64, D1=128 (all fp32 in/out).
// u[b,n1,n0,d1] = sum_d0 x[b,n0,d0]*W[n1,n0,d0,d1]
// s = sum_n0 u ; logit = (u . s)/sqrt(128) ; c = softmax_n1(logit) + bias
// out[b,n1,d1] = sum_n0 u*c
//
// ws layout: u bf16 [B][N1][N0][D1] @ 0 (268435456 B); xbf @ 268435456 (4 MB)
//
// RULES: (R4/R5) unified VGPR+AGPR <= 128/wave. (R8/R9) W nontemporal (L3
// kept for u). (R10) W read once structurally. (R11) K2/3/4 fused per-b.
// (R12) k234 16B/lane loads + row register-cache: one memory pass for s+logit.

#define BB 256
#define NN0 64
#define DD0 128
#define NN1 64
#define DD1 128

typedef __attribute__((ext_vector_type(8))) short bf16x8;
typedef __attribute__((ext_vector_type(4))) float f32x4;

__device__ __forceinline__ ushort f2bf(float f) {
  uint32_t b = __float_as_uint(f);
  b += 0x7FFFu + ((b >> 16) & 1u);      // RNE
  return (ushort)(b >> 16);
}
__device__ __forceinline__ float bf2f(ushort h) {
  return __uint_as_float(((uint32_t)h) << 16);
}

__device__ __forceinline__ void gld_lds16(const void* g, void* l) {
  __builtin_amdgcn_global_load_lds(
      (const __attribute__((address_space(1))) void*)g,
      (__attribute__((address_space(3))) void*)l, 16, 0, 0);
}

__device__ __forceinline__ void bar_lgkm() {
  asm volatile("s_waitcnt lgkmcnt(0)" ::: "memory");
  __builtin_amdgcn_s_barrier();
  __builtin_amdgcn_sched_barrier(0);
}

// ---------------- Px: x fp32 -> bf16 (single-use read: nontemporal)
__global__ __launch_bounds__(512) void px_cvt(
    const float* __restrict__ x, ushort* __restrict__ xbf)
{
  int i = blockIdx.x * 512 + threadIdx.x;
  const f32x4* src = reinterpret_cast<const f32x4*>(x) + i;
  f32x4 v = __builtin_nontemporal_load(src);
  ushort4 h;
  h.x = f2bf(v.x); h.y = f2bf(v.y); h.z = f2bf(v.z); h.w = f2bf(v.w);
  *reinterpret_cast<ushort4*>(xbf + (size_t)i * 4) = h;
}

// ---------------- K1: block = (n1, n0). M=256(b) x N=128(d1), K=128.
// (unchanged from R10: A staged once via global_load_lds, W read once nt,
// depth-2 reg pipeline, lgkm-only barriers; LDS 80KB -> 2 blocks/CU.)
__global__ __launch_bounds__(512, 4) void k1_gemm(
    const ushort* __restrict__ xbf, const float* __restrict__ W,
    ushort* __restrict__ u)
{
  __shared__ __align__(16) char lds[81920];
  char* Alds = lds;                          // 256 rows(b) x 256B (k=128), XOR-swz
  char* Bl[2] = { lds + 65536, lds + 73728 };// 128 rows(d1) x 64B (32 k), swz

  const int q = blockIdx.x;
  const int local = q >> 3;
  const int n0 = (q & 7) * 8 + (local >> 6);
  const int n1 = local & 63;
  const int t = threadIdx.x;
  const int lane = t & 63, wave = t >> 6;
  const int wm = wave >> 1, wn = wave & 1;   // 4 M-waves(64b) x 2 N-waves(64 d1)

  const ushort* xb = xbf + n0 * DD0;
  const float* Wb = W + ((size_t)n1 * NN0 + n0) * (DD0 * DD1);
  ushort* ub = u + ((size_t)n1 * 8192 + (size_t)n0 * 128);

  f32x4 acc[4][4];
#pragma unroll
  for (int a = 0; a < 4; ++a)
#pragma unroll
    for (int b = 0; b < 4; ++b) acc[a][b] = {0.f, 0.f, 0.f, 0.f};

  const int gd1 = t & 127, gkc = t >> 7;
  const int bbyte = (gd1 * 64 + gkc * 16) ^ ((gd1 & 3) << 4) ^ (((gd1 >> 2) & 1) << 6);
  float w0[8], w1[8];

#define LOADW(hh, ks)                                                         \
  {                                                                           \
    _Pragma("unroll")                                                         \
    for (int j = 0; j < 8; ++j)                                               \
      hh[j] = __builtin_nontemporal_load(                                     \
          Wb + (size_t)((ks) * 32 + gkc * 8 + j) * 128 + gd1);                \
  }
#define PACKB(bi, hh)                                                         \
  {                                                                           \
    uint32_t p0 = (uint32_t)f2bf(hh[0]) | ((uint32_t)f2bf(hh[1]) << 16);      \
    uint32_t p1 = (uint32_t)f2bf(hh[2]) | ((uint32_t)f2bf(hh[3]) << 16);      \
    uint32_t p2 = (uint32_t)f2bf(hh[4]) | ((uint32_t)f2bf(hh[5]) << 16);      \
    uint32_t p3 = (uint32_t)f2bf(hh[6]) | ((uint32_t)f2bf(hh[7]) << 16);      \
    *reinterpret_cast<uint4*>(Bl[bi] + bbyte) = make_uint4(p0, p1, p2, p3);   \
  }
#define MFMA_STEP(ks, bi)                                                     \
  {                                                                           \
    const int kb16 = (lane >> 4);                                             \
    const int ka = (ks) * 32 + kb16 * 8;                                      \
    bf16x8 af[4], bfr[4];                                                     \
    _Pragma("unroll")                                                         \
    for (int mf = 0; mf < 4; ++mf) {                                          \
      int row = wm * 64 + mf * 16 + (lane & 15);                              \
      int byte = (row * 256 + ka * 2) ^ ((row & 7) << 4);                     \
      af[mf] = *reinterpret_cast<const bf16x8*>(Alds + byte);                 \
    }                                                                         \
    _Pragma("unroll")                                                         \
    for (int nf = 0; nf < 4; ++nf) {                                          \
      int n = wn * 64 + nf * 16 + (lane & 15);                                \
      int byte = (n * 64 + kb16 * 16) ^ ((n & 3) << 4) ^ (((n >> 2) & 1) << 6); \
      bfr[nf] = *reinterpret_cast<const bf16x8*>(Bl[bi] + byte);              \
    }                                                                         \
    _Pragma("unroll")                                                         \
    for (int mf = 0; mf < 4; ++mf)                                            \
      _Pragma("unroll")                                                       \
      for (int nf = 0; nf < 4; ++nf)                                          \
        acc[mf][nf] = __builtin_amdgcn_mfma_f32_16x16x32_bf16(af[mf], bfr[nf], acc[mf][nf], 0, 0, 0); \
  }

#pragma unroll
  for (int s = 0; s < 8; ++s) {
    int seg = wave * 8 + s;
    int row = seg * 4 + (lane >> 4);
    int srcc = (lane & 15) ^ (row & 7);
    gld_lds16(xb + (size_t)row * 8192 + srcc * 8, Alds + seg * 1024);
  }
  __builtin_amdgcn_sched_barrier(0);
  LOADW(w0, 0);
  __builtin_amdgcn_sched_barrier(0);
  LOADW(w1, 1);
  __builtin_amdgcn_sched_barrier(0);
  PACKB(0, w0);
  LOADW(w0, 2);
  __builtin_amdgcn_sched_barrier(0);
  bar_lgkm();

  PACKB(1, w1);
  LOADW(w1, 3);
  __builtin_amdgcn_sched_barrier(0);
  MFMA_STEP(0, 0);
  bar_lgkm();

  PACKB(0, w0);
  __builtin_amdgcn_sched_barrier(0);
  MFMA_STEP(1, 1);
  bar_lgkm();

  PACKB(1, w1);
  __builtin_amdgcn_sched_barrier(0);
  MFMA_STEP(2, 0);
  bar_lgkm();

  MFMA_STEP(3, 1);

  bar_lgkm();
#pragma unroll
  for (int mf = 0; mf < 4; ++mf) {
#pragma unroll
    for (int nf = 0; nf < 4; ++nf) {
      int col = wn * 64 + nf * 16 + (lane & 15);
#pragma unroll
      for (int j = 0; j < 4; ++j) {
        int rr = wm * 64 + mf * 16 + (lane >> 4) * 4 + j;
        int byte = (rr * 256 + col * 2) ^ ((rr & 7) << 4);
        *reinterpret_cast<ushort*>(Alds + byte) = f2bf(acc[mf][nf][j]);
      }
    }
  }
  bar_lgkm();
#pragma unroll
  for (int ci = 0; ci < 8; ++ci) {
    int c = t + ci * 512;
    int rowl = c >> 4;
    int cb = (c & 15) * 16;
    int sbyte = (rowl * 256 + cb) ^ ((rowl & 7) << 4);
    uint4 v = *reinterpret_cast<uint4*>(Alds + sbyte);
    *reinterpret_cast<uint4*>(ub + (size_t)rowl * 524288 + cb / 2) = v;
  }
#undef LOADW
#undef PACKB
#undef MFMA_STEP
}

// ---------------- K234 fused v2: block = b. Lane (g=l>>4, c=l&15):
// covers n0 = q*4+g (q=0..15), d1-octet c. Per n1: ONE 16B load per q,
// rows cached in 64 VGPR; s via 2 shfl_xor; logit via 16-lane butterfly;
// softmax; out re-reads u (L2/L3) and reduces via 2 shfl_xor.
__global__ __launch_bounds__(512, 2) void k234_fused(
    const ushort* __restrict__ u, const float* __restrict__ bias,
    float* __restrict__ out)
{
  const int b = blockIdx.x;
  const ushort* ub = u + (size_t)b * 524288;      // [n1][n0][d1]
  const int t = threadIdx.x;
  const int lane = t & 63, w = t >> 6;
  const int g = lane >> 4, c = lane & 15;

  __shared__ float cL[64][65];                    // logits -> c (padded)
  __shared__ float red[2][8][64];                 // phase-C partials

  // ---- Phases A+B per n1 (single memory pass; rows register-cached)
#pragma unroll 1
  for (int i = 0; i < 8; ++i) {
    const int n1 = w * 8 + i;
    const ushort* base = ub + n1 * 8192 + g * 128 + c * 8;
    bf16x8 rows[16];
#pragma unroll
    for (int q = 0; q < 16; ++q)
      rows[q] = *reinterpret_cast<const bf16x8*>(base + q * 512);  // n0=q*4+g

    float s8[8];
#pragma unroll
    for (int j = 0; j < 8; ++j) s8[j] = 0.f;
#pragma unroll
    for (int q = 0; q < 16; ++q)
#pragma unroll
      for (int j = 0; j < 8; ++j) s8[j] += bf2f((ushort)rows[q][j]);
    // reduce across the 4 n0-groups -> full s for this d1 octet
#pragma unroll
    for (int j = 0; j < 8; ++j) {
      s8[j] += __shfl_xor(s8[j], 16, 64);
      s8[j] += __shfl_xor(s8[j], 32, 64);
    }
    // partial dots from cached rows
    float p[16];
#pragma unroll
    for (int q = 0; q < 16; ++q) {
      float a = 0.f;
#pragma unroll
      for (int j = 0; j < 8; ++j) a += bf2f((ushort)rows[q][j]) * s8[j];
      p[q] = a;
    }
    // 16-lane butterfly transpose-reduce (over c): lane ends with full
    // dot for q = c (same recurrence as R11's 64-wide version, verified)
#pragma unroll
    for (int s2 = 0; s2 < 4; ++s2) {
      const int kb = (c >> s2) & 1;
#pragma unroll
      for (int j = 0; j < (16 >> (s2 + 1)); ++j) {
        float a = p[2 * j], b2 = p[2 * j + 1];
        float mine = kb ? b2 : a;
        float send = kb ? a : b2;
        p[j] = mine + __shfl_xor(send, 1 << s2, 64);
      }
    }
    cL[n1][c * 4 + g] = p[0] * 0.08838834764831845f;   // /sqrt(128)
  }
  __syncthreads();

  // ---- Phase C: softmax over n1 (per n0) + bias; 8 groups of 8 n1
  {
    const int gg = t >> 6, n0 = t & 63;
    float pm = -1e30f;
#pragma unroll
    for (int j = 0; j < 8; ++j) pm = fmaxf(pm, cL[gg * 8 + j][n0]);
    red[0][gg][n0] = pm;
    __syncthreads();
    if (gg == 0) {
      float m = red[0][0][n0];
#pragma unroll
      for (int j = 1; j < 8; ++j) m = fmaxf(m, red[0][j][n0]);
      red[0][0][n0] = m;
    }
    __syncthreads();
    const float m = red[0][0][n0];
    float ps = 0.f;
#pragma unroll
    for (int j = 0; j < 8; ++j) {
      float e = __expf(cL[gg * 8 + j][n0] - m);
      cL[gg * 8 + j][n0] = e;
      ps += e;
    }
    red[1][gg][n0] = ps;
    __syncthreads();
    if (gg == 0) {
      float sm = 0.f;
#pragma unroll
      for (int j = 0; j < 8; ++j) sm += red[1][j][n0];
      red[1][0][n0] = 1.0f / sm;
    }
    __syncthreads();
    const float inv = red[1][0][n0];
#pragma unroll
    for (int j = 0; j < 8; ++j) {
      int n1 = gg * 8 + j;
      cL[n1][n0] = cL[n1][n0] * inv + bias[n1 * 64 + n0];
    }
  }
  __syncthreads();

  // ---- Phase D: out[n1][d1] = sum_n0 c[n1][n0]*u[n1][n0][d1] (u from L2/L3)
#pragma unroll 1
  for (int i = 0; i < 8; ++i) {
    const int n1 = w * 8 + i;
    const ushort* base = ub + n1 * 8192 + g * 128 + c * 8;
    float o8[8];
#pragma unroll
    for (int j = 0; j < 8; ++j) o8[j] = 0.f;
#pragma unroll
    for (int q = 0; q < 16; ++q) {
      bf16x8 v = *reinterpret_cast<const bf16x8*>(base + q * 512);
      float cc = cL[n1][q * 4 + g];
#pragma unroll
      for (int j = 0; j < 8; ++j) o8[j] += bf2f((ushort)v[j]) * cc;
    }
#pragma unroll
    for (int j = 0; j < 8; ++j) {
      o8[j] += __shfl_xor(o8[j], 16, 64);
      o8[j] += __shfl_xor(o8[j], 32, 64);
    }
    if (g == 0) {
      float* op = out + (size_t)b * 8192 + n1 * 128 + c * 8;
      f32x4 v0 = {o8[0], o8[1], o8[2], o8[3]};
      f32x4 v1 = {o8[4], o8[5], o8[6], o8[7]};
      *reinterpret_cast<f32x4*>(op) = v0;
      *reinterpret_cast<f32x4*>(op + 4) = v1;
    }
  }
}

extern "C" void kernel_launch(void* const* d_in, const int* in_sizes, int n_in,
                              void* d_out, int out_size, void* d_ws, size_t ws_size,
                              hipStream_t stream) {
  const float* x = (const float*)d_in[0];
  const float* W = (const float*)d_in[1];
  const float* bias = (const float*)d_in[2];
  float* out = (float*)d_out;

  ushort* u = (ushort*)d_ws;                            // 268435456 B
  ushort* xbf = (ushort*)((char*)d_ws + 268435456u);    // 4194304 B

  hipLaunchKernelGGL(px_cvt,     dim3(1024), dim3(512), 0, stream, x, xbf);
  hipLaunchKernelGGL(k1_gemm,    dim3(4096), dim3(512), 0, stream, xbf, W, u);
  hipLaunchKernelGGL(k234_fused, dim3(BB),   dim3(512), 0, stream, u, bias, out);
}

// Round 13
// 178.741 us; speedup vs baseline: 1.1469x; 1.0122x over previous
//
#include <hip/hip_runtime.h>
#include <hip/hip_bf16.h>
#include <cstdint>

// Problem: B=256, N0=64, D0=128, N1=64, D1=128 (all fp32 in/out).
// u[b,n1,n0,d1] = sum_d0 x[b,n0,d0]*W[n1,n0,d0,d1]
// s = sum_n0 u ; logit = (u . s)/sqrt(128) ; c = softmax_n1(logit) + bias
// out[b,n1,d1] = sum_n0 u*c
//
// ws layout: u bf16 [B][N1][N0][D1] @ 0 (268435456 B); xbf @ 268435456 (4 MB)
//
// RULES: (R4/R5) unified VGPR+AGPR <= 128/wave. (R8/R9) W nontemporal (L3
// kept for u). (R10) W read once structurally. (R11) K2/3/4 fused per-b.
// (R12) k234 16B/lane loads + row register-cache. (R13) phase D runs n1 in
// REVERSE (LIFO reuse of phase-A lines) with nt loads (last reader).

#define BB 256
#define NN0 64
#define DD0 128
#define NN1 64
#define DD1 128

typedef __attribute__((ext_vector_type(8))) short bf16x8;
typedef __attribute__((ext_vector_type(4))) float f32x4;

__device__ __forceinline__ ushort f2bf(float f) {
  uint32_t b = __float_as_uint(f);
  b += 0x7FFFu + ((b >> 16) & 1u);      // RNE
  return (ushort)(b >> 16);
}
__device__ __forceinline__ float bf2f(ushort h) {
  return __uint_as_float(((uint32_t)h) << 16);
}

__device__ __forceinline__ void gld_lds16(const void* g, void* l) {
  __builtin_amdgcn_global_load_lds(
      (const __attribute__((address_space(1))) void*)g,
      (__attribute__((address_space(3))) void*)l, 16, 0, 0);
}

__device__ __forceinline__ void bar_lgkm() {
  asm volatile("s_waitcnt lgkmcnt(0)" ::: "memory");
  __builtin_amdgcn_s_barrier();
  __builtin_amdgcn_sched_barrier(0);
}

// ---------------- Px: x fp32 -> bf16 (single-use read: nontemporal)
__global__ __launch_bounds__(512) void px_cvt(
    const float* __restrict__ x, ushort* __restrict__ xbf)
{
  int i = blockIdx.x * 512 + threadIdx.x;
  const f32x4* src = reinterpret_cast<const f32x4*>(x) + i;
  f32x4 v = __builtin_nontemporal_load(src);
  ushort4 h;
  h.x = f2bf(v.x); h.y = f2bf(v.y); h.z = f2bf(v.z); h.w = f2bf(v.w);
  *reinterpret_cast<ushort4*>(xbf + (size_t)i * 4) = h;
}

// ---------------- K1: block = (n1, n0). M=256(b) x N=128(d1), K=128.
// (unchanged from R10: A staged once via global_load_lds, W read once nt,
// depth-2 reg pipeline, lgkm-only barriers; LDS 80KB -> 2 blocks/CU.)
__global__ __launch_bounds__(512, 4) void k1_gemm(
    const ushort* __restrict__ xbf, const float* __restrict__ W,
    ushort* __restrict__ u)
{
  __shared__ __align__(16) char lds[81920];
  char* Alds = lds;                          // 256 rows(b) x 256B (k=128), XOR-swz
  char* Bl[2] = { lds + 65536, lds + 73728 };// 128 rows(d1) x 64B (32 k), swz

  const int q = blockIdx.x;
  const int local = q >> 3;
  const int n0 = (q & 7) * 8 + (local >> 6);
  const int n1 = local & 63;
  const int t = threadIdx.x;
  const int lane = t & 63, wave = t >> 6;
  const int wm = wave >> 1, wn = wave & 1;   // 4 M-waves(64b) x 2 N-waves(64 d1)

  const ushort* xb = xbf + n0 * DD0;
  const float* Wb = W + ((size_t)n1 * NN0 + n0) * (DD0 * DD1);
  ushort* ub = u + ((size_t)n1 * 8192 + (size_t)n0 * 128);

  f32x4 acc[4][4];
#pragma unroll
  for (int a = 0; a < 4; ++a)
#pragma unroll
    for (int b = 0; b < 4; ++b) acc[a][b] = {0.f, 0.f, 0.f, 0.f};

  const int gd1 = t & 127, gkc = t >> 7;
  const int bbyte = (gd1 * 64 + gkc * 16) ^ ((gd1 & 3) << 4) ^ (((gd1 >> 2) & 1) << 6);
  float w0[8], w1[8];

#define LOADW(hh, ks)                                                         \
  {                                                                           \
    _Pragma("unroll")                                                         \
    for (int j = 0; j < 8; ++j)                                               \
      hh[j] = __builtin_nontemporal_load(                                     \
          Wb + (size_t)((ks) * 32 + gkc * 8 + j) * 128 + gd1);                \
  }
#define PACKB(bi, hh)                                                         \
  {                                                                           \
    uint32_t p0 = (uint32_t)f2bf(hh[0]) | ((uint32_t)f2bf(hh[1]) << 16);      \
    uint32_t p1 = (uint32_t)f2bf(hh[2]) | ((uint32_t)f2bf(hh[3]) << 16);      \
    uint32_t p2 = (uint32_t)f2bf(hh[4]) | ((uint32_t)f2bf(hh[5]) << 16);      \
    uint32_t p3 = (uint32_t)f2bf(hh[6]) | ((uint32_t)f2bf(hh[7]) << 16);      \
    *reinterpret_cast<uint4*>(Bl[bi] + bbyte) = make_uint4(p0, p1, p2, p3);   \
  }
#define MFMA_STEP(ks, bi)                                                     \
  {                                                                           \
    const int kb16 = (lane >> 4);                                             \
    const int ka = (ks) * 32 + kb16 * 8;                                      \
    bf16x8 af[4], bfr[4];                                                     \
    _Pragma("unroll")                                                         \
    for (int mf = 0; mf < 4; ++mf) {                                          \
      int row = wm * 64 + mf * 16 + (lane & 15);                              \
      int byte = (row * 256 + ka * 2) ^ ((row & 7) << 4);                     \
      af[mf] = *reinterpret_cast<const bf16x8*>(Alds + byte);                 \
    }                                                                         \
    _Pragma("unroll")                                                         \
    for (int nf = 0; nf < 4; ++nf) {                                          \
      int n = wn * 64 + nf * 16 + (lane & 15);                                \
      int byte = (n * 64 + kb16 * 16) ^ ((n & 3) << 4) ^ (((n >> 2) & 1) << 6); \
      bfr[nf] = *reinterpret_cast<const bf16x8*>(Bl[bi] + byte);              \
    }                                                                         \
    _Pragma("unroll")                                                         \
    for (int mf = 0; mf < 4; ++mf)                                            \
      _Pragma("unroll")                                                       \
      for (int nf = 0; nf < 4; ++nf)                                          \
        acc[mf][nf] = __builtin_amdgcn_mfma_f32_16x16x32_bf16(af[mf], bfr[nf], acc[mf][nf], 0, 0, 0); \
  }

#pragma unroll
  for (int s = 0; s < 8; ++s) {
    int seg = wave * 8 + s;
    int row = seg * 4 + (lane >> 4);
    int srcc = (lane & 15) ^ (row & 7);
    gld_lds16(xb + (size_t)row * 8192 + srcc * 8, Alds + seg * 1024);
  }
  __builtin_amdgcn_sched_barrier(0);
  LOADW(w0, 0);
  __builtin_amdgcn_sched_barrier(0);
  LOADW(w1, 1);
  __builtin_amdgcn_sched_barrier(0);
  PACKB(0, w0);
  LOADW(w0, 2);
  __builtin_amdgcn_sched_barrier(0);
  bar_lgkm();

  PACKB(1, w1);
  LOADW(w1, 3);
  __builtin_amdgcn_sched_barrier(0);
  MFMA_STEP(0, 0);
  bar_lgkm();

  PACKB(0, w0);
  __builtin_amdgcn_sched_barrier(0);
  MFMA_STEP(1, 1);
  bar_lgkm();

  PACKB(1, w1);
  __builtin_amdgcn_sched_barrier(0);
  MFMA_STEP(2, 0);
  bar_lgkm();

  MFMA_STEP(3, 1);

  bar_lgkm();
#pragma unroll
  for (int mf = 0; mf < 4; ++mf) {
#pragma unroll
    for (int nf = 0; nf < 4; ++nf) {
      int col = wn * 64 + nf * 16 + (lane & 15);
#pragma unroll
      for (int j = 0; j < 4; ++j) {
        int rr = wm * 64 + mf * 16 + (lane >> 4) * 4 + j;
        int byte = (rr * 256 + col * 2) ^ ((rr & 7) << 4);
        *reinterpret_cast<ushort*>(Alds + byte) = f2bf(acc[mf][nf][j]);
      }
    }
  }
  bar_lgkm();
#pragma unroll
  for (int ci = 0; ci < 8; ++ci) {
    int c = t + ci * 512;
    int rowl = c >> 4;
    int cb = (c & 15) * 16;
    int sbyte = (rowl * 256 + cb) ^ ((rowl & 7) << 4);
    uint4 v = *reinterpret_cast<uint4*>(Alds + sbyte);
    *reinterpret_cast<uint4*>(ub + (size_t)rowl * 524288 + cb / 2) = v;
  }
#undef LOADW
#undef PACKB
#undef MFMA_STEP
}

// ---------------- K234 fused v3: block = b. Lane (g=l>>4, c=l&15):
// covers n0 = q*4+g (q=0..15), d1-octet c. Per n1: ONE 16B load per q,
// rows cached in 64 VGPR; s via 2 shfl_xor; logit via 16-lane butterfly;
// softmax; phase D iterates n1 in REVERSE (LIFO L3/L2 reuse of phase-A
// lines) with nontemporal loads (last reader).
__global__ __launch_bounds__(512, 2) void k234_fused(
    const ushort* __restrict__ u, const float* __restrict__ bias,
    float* __restrict__ out)
{
  const int b = blockIdx.x;
  const ushort* ub = u + (size_t)b * 524288;      // [n1][n0][d1]
  const int t = threadIdx.x;
  const int lane = t & 63, w = t >> 6;
  const int g = lane >> 4, c = lane & 15;

  __shared__ float cL[64][65];                    // logits -> c (padded)
  __shared__ float red[2][8][64];                 // phase-C partials

  // ---- Phases A+B per n1 (single memory pass; rows register-cached)
#pragma unroll 1
  for (int i = 0; i < 8; ++i) {
    const int n1 = w * 8 + i;
    const ushort* base = ub + n1 * 8192 + g * 128 + c * 8;
    bf16x8 rows[16];
#pragma unroll
    for (int q = 0; q < 16; ++q)
      rows[q] = *reinterpret_cast<const bf16x8*>(base + q * 512);  // n0=q*4+g

    float s8[8];
#pragma unroll
    for (int j = 0; j < 8; ++j) s8[j] = 0.f;
#pragma unroll
    for (int q = 0; q < 16; ++q)
#pragma unroll
      for (int j = 0; j < 8; ++j) s8[j] += bf2f((ushort)rows[q][j]);
    // reduce across the 4 n0-groups -> full s for this d1 octet
#pragma unroll
    for (int j = 0; j < 8; ++j) {
      s8[j] += __shfl_xor(s8[j], 16, 64);
      s8[j] += __shfl_xor(s8[j], 32, 64);
    }
    // partial dots from cached rows
    float p[16];
#pragma unroll
    for (int q = 0; q < 16; ++q) {
      float a = 0.f;
#pragma unroll
      for (int j = 0; j < 8; ++j) a += bf2f((ushort)rows[q][j]) * s8[j];
      p[q] = a;
    }
    // 16-lane butterfly transpose-reduce (over c): lane ends with full
    // dot for q = c (same recurrence as R11's 64-wide version, verified)
#pragma unroll
    for (int s2 = 0; s2 < 4; ++s2) {
      const int kb = (c >> s2) & 1;
#pragma unroll
      for (int j = 0; j < (16 >> (s2 + 1)); ++j) {
        float a = p[2 * j], b2 = p[2 * j + 1];
        float mine = kb ? b2 : a;
        float send = kb ? a : b2;
        p[j] = mine + __shfl_xor(send, 1 << s2, 64);
      }
    }
    cL[n1][c * 4 + g] = p[0] * 0.08838834764831845f;   // /sqrt(128)
  }
  __syncthreads();

  // ---- Phase C: softmax over n1 (per n0) + bias; 8 groups of 8 n1
  {
    const int gg = t >> 6, n0 = t & 63;
    float pm = -1e30f;
#pragma unroll
    for (int j = 0; j < 8; ++j) pm = fmaxf(pm, cL[gg * 8 + j][n0]);
    red[0][gg][n0] = pm;
    __syncthreads();
    if (gg == 0) {
      float m = red[0][0][n0];
#pragma unroll
      for (int j = 1; j < 8; ++j) m = fmaxf(m, red[0][j][n0]);
      red[0][0][n0] = m;
    }
    __syncthreads();
    const float m = red[0][0][n0];
    float ps = 0.f;
#pragma unroll
    for (int j = 0; j < 8; ++j) {
      float e = __expf(cL[gg * 8 + j][n0] - m);
      cL[gg * 8 + j][n0] = e;
      ps += e;
    }
    red[1][gg][n0] = ps;
    __syncthreads();
    if (gg == 0) {
      float sm = 0.f;
#pragma unroll
      for (int j = 0; j < 8; ++j) sm += red[1][j][n0];
      red[1][0][n0] = 1.0f / sm;
    }
    __syncthreads();
    const float inv = red[1][0][n0];
#pragma unroll
    for (int j = 0; j < 8; ++j) {
      int n1 = gg * 8 + j;
      cL[n1][n0] = cL[n1][n0] * inv + bias[n1 * 64 + n0];
    }
  }
  __syncthreads();

  // ---- Phase D (REVERSED n1, nt loads): out[n1][d1] = sum_n0 c*u
#pragma unroll 1
  for (int i = 7; i >= 0; --i) {
    const int n1 = w * 8 + i;
    const ushort* base = ub + n1 * 8192 + g * 128 + c * 8;
    float o8[8];
#pragma unroll
    for (int j = 0; j < 8; ++j) o8[j] = 0.f;
#pragma unroll
    for (int q = 0; q < 16; ++q) {
      bf16x8 v = __builtin_nontemporal_load(
          reinterpret_cast<const bf16x8*>(base + q * 512));
      float cc = cL[n1][q * 4 + g];
#pragma unroll
      for (int j = 0; j < 8; ++j) o8[j] += bf2f((ushort)v[j]) * cc;
    }
#pragma unroll
    for (int j = 0; j < 8; ++j) {
      o8[j] += __shfl_xor(o8[j], 16, 64);
      o8[j] += __shfl_xor(o8[j], 32, 64);
    }
    if (g == 0) {
      float* op = out + (size_t)b * 8192 + n1 * 128 + c * 8;
      f32x4 v0 = {o8[0], o8[1], o8[2], o8[3]};
      f32x4 v1 = {o8[4], o8[5], o8[6], o8[7]};
      *reinterpret_cast<f32x4*>(op) = v0;
      *reinterpret_cast<f32x4*>(op + 4) = v1;
    }
  }
}

extern "C" void kernel_launch(void* const* d_in, const int* in_sizes, int n_in,
                              void* d_out, int out_size, void* d_ws, size_t ws_size,
                              hipStream_t stream) {
  const float* x = (const float*)d_in[0];
  const float* W = (const float*)d_in[1];
  const float* bias = (const float*)d_in[2];
  float* out = (float*)d_out;

  ushort* u = (ushort*)d_ws;                            // 268435456 B
  ushort* xbf = (ushort*)((char*)d_ws + 268435456u);    // 4194304 B

  hipLaunchKernelGGL(px_cvt,     dim3(1024), dim3(512), 0, stream, x, xbf);
  hipLaunchKernelGGL(k1_gemm,    dim3(4096), dim3(512), 0, stream, xbf, W, u);
  hipLaunchKernelGGL(k234_fused, dim3(BB),   dim3(512), 0, stream, u, bias, out);
}